// Round 4
// baseline (777.502 us; speedup 1.0000x reference)
//
#include <hip/hip_runtime.h>

typedef _Float16 f16;
typedef _Float16 f16x8 __attribute__((ext_vector_type(8)));
typedef _Float16 f16x4 __attribute__((ext_vector_type(4)));
typedef float    f32x4 __attribute__((ext_vector_type(4)));
typedef float    f32x16 __attribute__((ext_vector_type(16)));

#define NB 4
#define SEQ 4096
#define DIM 512
#define MTOT (NB*SEQ)   // 16384
#define NEL ((size_t)MTOT*DIM)

// ---------------------------------------------------------------------------
// Projection GEMM: out[m,n] = f16( sum_k A[m,k] * W[n,k] + bias[n] )
// p: 0:q natural  1:qv natural  2:k fragment-packed  3:kv fragment-packed
// Packed layouts (unit = 16B = 8 f16, per 32-row KV tile gt = g>>5):
//  K: u = ((gt*2 + h)*16 + s)*64 + hi*32 + col   elem j
//     where col=g&31, d = h*256 + s*16 + hi*8 + j
//     -> wave QK^T B-frag load for (tile,h,step s) = 1KB contiguous
//  V: u = ((gt*16 + c32)*2 + ks)*64 + hi*32 + cl  elem j
//     where kv=g&31 = ks*16+hi*8+j, d = c32*32 + cl
//     -> wave PV B-frag load for (tile,c32,ks) = 1KB contiguous
// ---------------------------------------------------------------------------
__global__ __launch_bounds__(256) void proj_gemm(
    const float* __restrict__ x, const float* __restrict__ y,
    const float* __restrict__ Wq, const float* __restrict__ bq,
    const float* __restrict__ Wqv, const float* __restrict__ bqv,
    const float* __restrict__ Wk, const float* __restrict__ bk,
    const float* __restrict__ Wkv, const float* __restrict__ bkv,
    f16* __restrict__ qh, f16* __restrict__ qvh,
    f16* __restrict__ kP, f16* __restrict__ vP)
{
    __shared__ __attribute__((aligned(16))) f16 a_lds[128][40];
    __shared__ __attribute__((aligned(16))) f16 b_lds[128][40];

    const int p = blockIdx.z;
    const float* A    = (p < 2) ? x : y;
    const float* W    = (p==0)?Wq:(p==1)?Wqv:(p==2)?Wk:Wkv;
    const float* bias = (p==0)?bq:(p==1)?bqv:(p==2)?bk:bkv;

    const int m0 = blockIdx.y * 128, n0 = blockIdx.x * 128;
    const int tid = threadIdx.x, lane = tid & 63, wv = tid >> 6;
    const int wm = wv >> 1, wn = wv & 1, mrow = lane & 15, qd = lane >> 4;

    f32x4 acc[4][4];
#pragma unroll
    for (int mt = 0; mt < 4; ++mt)
#pragma unroll
        for (int nt = 0; nt < 4; ++nt) acc[mt][nt] = (f32x4){0.f,0.f,0.f,0.f};

    float bv[4];
#pragma unroll
    for (int nt = 0; nt < 4; ++nt) bv[nt] = bias[n0 + wn*64 + nt*16 + mrow];

    for (int k0 = 0; k0 < DIM; k0 += 32) {
        __syncthreads();
#pragma unroll
        for (int i = 0; i < 4; ++i) {
            int c = i*256 + tid;
            int row = c >> 3, c4 = c & 7;
            float4 v = *(const float4*)(A + (size_t)(m0+row)*DIM + k0 + c4*4);
            f16x4 hh = { (f16)v.x, (f16)v.y, (f16)v.z, (f16)v.w };
            *(f16x4*)&a_lds[row][c4*4] = hh;
        }
#pragma unroll
        for (int i = 0; i < 4; ++i) {
            int c = i*256 + tid;
            int row = c >> 3, c4 = c & 7;
            float4 v = *(const float4*)(W + (size_t)(n0+row)*DIM + k0 + c4*4);
            f16x4 hh = { (f16)v.x, (f16)v.y, (f16)v.z, (f16)v.w };
            *(f16x4*)&b_lds[row][c4*4] = hh;
        }
        __syncthreads();
        f16x8 af[4], bfr[4];
#pragma unroll
        for (int mt = 0; mt < 4; ++mt) af[mt]  = *(const f16x8*)&a_lds[wm*64 + mt*16 + mrow][qd*8];
#pragma unroll
        for (int nt = 0; nt < 4; ++nt) bfr[nt] = *(const f16x8*)&b_lds[wn*64 + nt*16 + mrow][qd*8];
#pragma unroll
        for (int mt = 0; mt < 4; ++mt)
#pragma unroll
            for (int nt = 0; nt < 4; ++nt)
                acc[mt][nt] = __builtin_amdgcn_mfma_f32_16x16x32_f16(af[mt], bfr[nt], acc[mt][nt], 0,0,0);
    }

#pragma unroll
    for (int mt = 0; mt < 4; ++mt)
#pragma unroll
        for (int r = 0; r < 4; ++r) {
            int g = m0 + wm*64 + mt*16 + qd*4 + r;
#pragma unroll
            for (int nt = 0; nt < 4; ++nt) {
                int d = n0 + wn*64 + nt*16 + mrow;
                f16 val = (f16)(acc[mt][nt][r] + bv[nt]);
                if (p == 0) {
                    qh[(size_t)g*DIM + d] = val;
                } else if (p == 1) {
                    qvh[(size_t)g*DIM + d] = val;
                } else if (p == 2) {
                    int gt = g >> 5, col = g & 31;
                    int h2 = d >> 8, dl = d & 255;
                    int s = dl >> 4, hi = (dl >> 3) & 1, j = d & 7;
                    size_t u = ((size_t)(gt*2 + h2)*16 + s)*64 + hi*32 + col;
                    kP[u*8 + j] = val;
                } else {
                    int gt = g >> 5, kvr = g & 31;
                    int ks = kvr >> 4, hi = (kvr >> 3) & 1, jj = kvr & 7;
                    int c32 = d >> 5, cl2 = d & 31;
                    size_t u = ((size_t)(gt*16 + c32)*2 + ks)*64 + hi*32 + cl2;
                    vP[u*8 + jj] = val;
                }
            }
        }
}

// ---------------------------------------------------------------------------
// max over each 32-lane group (all lanes receive result). 4x DPP row_shr
// (VALU pipe) + 2 ds_swizzle broadcasts of lanes 15/31 within the group.
// bound_ctrl=false keeps old value in invalid lanes (max(v,v)=v: safe).
// ---------------------------------------------------------------------------
__device__ __forceinline__ float rowmax32(float v)
{
    int x;
    x = __builtin_amdgcn_update_dpp(__builtin_bit_cast(int, v), __builtin_bit_cast(int, v), 0x111, 0xF, 0xF, false);
    v = fmaxf(v, __builtin_bit_cast(float, x));
    x = __builtin_amdgcn_update_dpp(__builtin_bit_cast(int, v), __builtin_bit_cast(int, v), 0x112, 0xF, 0xF, false);
    v = fmaxf(v, __builtin_bit_cast(float, x));
    x = __builtin_amdgcn_update_dpp(__builtin_bit_cast(int, v), __builtin_bit_cast(int, v), 0x114, 0xF, 0xF, false);
    v = fmaxf(v, __builtin_bit_cast(float, x));
    x = __builtin_amdgcn_update_dpp(__builtin_bit_cast(int, v), __builtin_bit_cast(int, v), 0x118, 0xF, 0xF, false);
    v = fmaxf(v, __builtin_bit_cast(float, x));
    float a = __builtin_bit_cast(float, __builtin_amdgcn_ds_swizzle(__builtin_bit_cast(int, v), 0x01E0)); // lane 15
    float b = __builtin_bit_cast(float, __builtin_amdgcn_ds_swizzle(__builtin_bit_cast(int, v), 0x03E0)); // lane 31
    return fmaxf(a, b);
}

// ---------------------------------------------------------------------------
// Flash attention v5: 256 blocks (1/CU), 512 thr / 8 waves (2/SIMD).
// K/V NEVER staged in LDS: MFMA B-fragments are loaded straight from the
// fragment-packed global layouts (1KB contiguous per wave-load, L2-resident
// via XCD-lockstep sweep). 32x32x16 MFMA amortizes each fragment over 32 Q
// rows. Waves: qg(2: 32 Q rows) x h(2: d-half for QK^T) x par(2: tile pair).
// Per iteration (2 tiles = 64 KV rows):
//   QK^T partial (16 mfma) -> 4-way LDS exchange -> both full S tiles
//   joint row-max (DPP) + defer-max(THR=8) -> exp (h==0 writes P to LDS)
//   PV: each wave owns d-quarter dq=2h+par, contracts BOTH tiles (16 mfma)
//   l via ones-MFMA (both tiles, every wave) -> no end-merge needed.
// LDS: xch 32KB + P 10KB = 42KB. 2 barriers/iter, ~270 LDS ops/iter total.
// ---------------------------------------------------------------------------
__global__ __launch_bounds__(512, 2) void attn_kernel(
    const f16* __restrict__ qh, const f16* __restrict__ kP,
    const f16* __restrict__ vP, const f16* __restrict__ qvh,
    f16* __restrict__ ao)
{
    __shared__ __attribute__((aligned(16))) f32x4 xch[2][4][4][64]; // 32KB
    __shared__ __attribute__((aligned(16))) f16 plds[2][2][32][40]; // 10KB

    const int xcd = blockIdx.x & 7;
    const int b   = xcd >> 1;                          // batch -> XCD pair
    const int qt  = (blockIdx.x >> 3) * 2 + (xcd & 1); // 0..63
    const int tid = threadIdx.x, lane = tid & 63, w = tid >> 6;
    const int qg = w & 1, h = (w >> 1) & 1, par = w >> 2;
    const int slot = w >> 1;                           // h + 2*par
    const int dq = h*2 + par;                          // d-quarter for PV
    const int cl = lane & 31, lh = lane >> 5;

    // Q A-frags for this wave's 256-d half: row = cl, k = s*16 + lh*8 + j
    const size_t qoff = ((size_t)b*SEQ + qt*64 + qg*32 + cl)*DIM + h*256 + lh*8;
    f16x8 qf[16];
#pragma unroll
    for (int s = 0; s < 16; ++s) qf[s] = *(const f16x8*)(qh + qoff + s*16);

    // K stream: (tile,h) block = 8192 f16; step s = 512 f16; lane*8
    const f16* kbase = kP + ((size_t)(b*128)*2 + h) * 8192;
    // V stream: (tile) block = 16384 f16; c32 = 1024; ks = 512; lane*8
    const f16* vbase = vP + ((size_t)(b*128)*16 + dq*4) * 1024;

    f32x16 o_[4];      // O[32 x (dq quarter: 4 col-tiles of 32)]
    f32x16 l16, m16;
#pragma unroll
    for (int i = 0; i < 16; ++i) {
        o_[0][i] = 0.f; o_[1][i] = 0.f; o_[2][i] = 0.f; o_[3][i] = 0.f;
        l16[i] = 0.f; m16[i] = -INFINITY;
    }
    const f16x8 onesv = {(f16)1.f,(f16)1.f,(f16)1.f,(f16)1.f,
                         (f16)1.f,(f16)1.f,(f16)1.f,(f16)1.f};

    for (int j = 0; j < 64; ++j) {
        // --- QK^T partial: S_part[32x32] for tile (2j+par), d-half h ---
        const f16* kt = kbase + (size_t)(2*j + par) * 16384;
        f32x16 sacc;
#pragma unroll
        for (int i = 0; i < 16; ++i) sacc[i] = 0.f;
#pragma unroll
        for (int s = 0; s < 16; ++s) {
            f16x8 kf = *(const f16x8*)(kt + s*512 + lane*8);
            sacc = __builtin_amdgcn_mfma_f32_32x32x16_f16(qf[s], kf, sacc, 0,0,0);
        }
#pragma unroll
        for (int ch = 0; ch < 4; ++ch) {
            f32x4 t = { sacc[ch*4], sacc[ch*4+1], sacc[ch*4+2], sacc[ch*4+3] };
            xch[qg][slot][ch][lane] = t;
        }
        __syncthreads();                                   // bar1: partials ready

        // --- build both full S tiles (sum over h) ---
        f32x16 S0, S1;
#pragma unroll
        for (int ch = 0; ch < 4; ++ch) {
            f32x4 p0 = xch[qg][0][ch][lane], p1 = xch[qg][1][ch][lane];
            f32x4 p2 = xch[qg][2][ch][lane], p3 = xch[qg][3][ch][lane];
#pragma unroll
            for (int r = 0; r < 4; ++r) {
                S0[ch*4+r] = p0[r] + p1[r];
                S1[ch*4+r] = p2[r] + p3[r];
            }
        }

        // --- V(t0) prefetch (crosses bar2 under softmax cover) ---
        const f16* vt0 = vbase + (size_t)(2*j) * 16384;
        f16x8 vs0[8];
#pragma unroll
        for (int c = 0; c < 4; ++c)
#pragma unroll
            for (int ks = 0; ks < 2; ++ks)
                vs0[c*2+ks] = *(const f16x8*)(vt0 + c*1024 + ks*512 + lane*8);

        // --- joint softmax state (defer-max THR=8) ---
        f32x16 pm;
#pragma unroll
        for (int i = 0; i < 16; ++i) pm[i] = rowmax32(fmaxf(S0[i], S1[i]));
        bool need = false;
#pragma unroll
        for (int i = 0; i < 16; ++i) need = need || (pm[i] > m16[i] + 8.f);
        if (__any((int)need)) {
#pragma unroll
            for (int i = 0; i < 16; ++i) {
                float mn = fmaxf(m16[i], pm[i]);
                float al = __expf(m16[i] - mn);
                m16[i] = mn;
                o_[0][i] *= al; o_[1][i] *= al; o_[2][i] *= al; o_[3][i] *= al;
                l16[i] *= al;
            }
        }
        if (h == 0) {   // wave (qg,0,par) writes P(tile par)
#pragma unroll
            for (int i = 0; i < 16; ++i) {
                float sv = (par == 0) ? S0[i] : S1[i];
                int row = (i & 3) + 8*(i >> 2) + 4*lh;
                plds[qg][par][row][cl] = (f16)__expf(sv - m16[i]);
            }
        }
        __syncthreads();                                   // bar2: P ready

        // --- PV: O_quarter += P(t0) V(t0) + P(t1) V(t1) ---
        f16x8 pa0 = *(const f16x8*)&plds[qg][0][cl][lh*8];
        f16x8 pa1 = *(const f16x8*)&plds[qg][0][cl][16 + lh*8];
        const f16* vt1 = vt0 + 16384;
        f16x8 vsx[4];
#pragma unroll
        for (int ks = 0; ks < 2; ++ks) {
            vsx[ks]   = *(const f16x8*)(vt1 + 0*1024 + ks*512 + lane*8);
            vsx[2+ks] = *(const f16x8*)(vt1 + 1*1024 + ks*512 + lane*8);
        }
        l16 = __builtin_amdgcn_mfma_f32_32x32x16_f16(pa0, onesv, l16, 0,0,0);
        l16 = __builtin_amdgcn_mfma_f32_32x32x16_f16(pa1, onesv, l16, 0,0,0);
#pragma unroll
        for (int c = 0; c < 4; ++c) {
            o_[c] = __builtin_amdgcn_mfma_f32_32x32x16_f16(pa0, vs0[c*2],   o_[c], 0,0,0);
            o_[c] = __builtin_amdgcn_mfma_f32_32x32x16_f16(pa1, vs0[c*2+1], o_[c], 0,0,0);
        }
        f16x8 pb0 = *(const f16x8*)&plds[qg][1][cl][lh*8];
        f16x8 pb1 = *(const f16x8*)&plds[qg][1][cl][16 + lh*8];
        l16 = __builtin_amdgcn_mfma_f32_32x32x16_f16(pb0, onesv, l16, 0,0,0);
        l16 = __builtin_amdgcn_mfma_f32_32x32x16_f16(pb1, onesv, l16, 0,0,0);
        o_[0] = __builtin_amdgcn_mfma_f32_32x32x16_f16(pb0, vsx[0], o_[0], 0,0,0);
        o_[0] = __builtin_amdgcn_mfma_f32_32x32x16_f16(pb1, vsx[1], o_[0], 0,0,0);
        o_[1] = __builtin_amdgcn_mfma_f32_32x32x16_f16(pb0, vsx[2], o_[1], 0,0,0);
        o_[1] = __builtin_amdgcn_mfma_f32_32x32x16_f16(pb1, vsx[3], o_[1], 0,0,0);
#pragma unroll
        for (int ks = 0; ks < 2; ++ks) {
            vsx[ks]   = *(const f16x8*)(vt1 + 2*1024 + ks*512 + lane*8);
            vsx[2+ks] = *(const f16x8*)(vt1 + 3*1024 + ks*512 + lane*8);
        }
        o_[2] = __builtin_amdgcn_mfma_f32_32x32x16_f16(pb0, vsx[0], o_[2], 0,0,0);
        o_[2] = __builtin_amdgcn_mfma_f32_32x32x16_f16(pb1, vsx[1], o_[2], 0,0,0);
        o_[3] = __builtin_amdgcn_mfma_f32_32x32x16_f16(pb0, vsx[2], o_[3], 0,0,0);
        o_[3] = __builtin_amdgcn_mfma_f32_32x32x16_f16(pb1, vsx[3], o_[3], 0,0,0);
    }

    // epilogue: rows qt*64+qg*32+row, cols dq*128 + c*32 + cl
#pragma unroll
    for (int i = 0; i < 16; ++i) {
        float inv = 1.f / l16[i];
        int row = (i & 3) + 8*(i >> 2) + 4*lh;
        size_t grow = ((size_t)b*SEQ + qt*64 + qg*32 + row)*DIM + dq*128;
#pragma unroll
        for (int c = 0; c < 4; ++c) {
            float val = o_[c][i]*inv + (float)qvh[grow + c*32 + cl];
            ao[grow + c*32 + cl] = (f16)val;
        }
    }
}

// ---------------------------------------------------------------------------
// Final linear: out[m,n] = sum_k ao[m,k]*Wf[n,k] + bf[n]  (f32 out)
// ---------------------------------------------------------------------------
__global__ __launch_bounds__(256) void final_gemm(
    const f16* __restrict__ ao, const float* __restrict__ Wf,
    const float* __restrict__ bf, float* __restrict__ out)
{
    __shared__ __attribute__((aligned(16))) f16 a_lds[128][40];
    __shared__ __attribute__((aligned(16))) f16 b_lds[128][40];

    const int m0 = blockIdx.y * 128, n0 = blockIdx.x * 128;
    const int tid = threadIdx.x, lane = tid & 63, wv = tid >> 6;
    const int wm = wv >> 1, wn = wv & 1, mrow = lane & 15, qd = lane >> 4;

    f32x4 acc[4][4];
#pragma unroll
    for (int mt = 0; mt < 4; ++mt)
#pragma unroll
        for (int nt = 0; nt < 4; ++nt) acc[mt][nt] = (f32x4){0.f,0.f,0.f,0.f};

    float bv[4];
#pragma unroll
    for (int nt = 0; nt < 4; ++nt) bv[nt] = bf[n0 + wn*64 + nt*16 + mrow];

    for (int k0 = 0; k0 < DIM; k0 += 32) {
        __syncthreads();
#pragma unroll
        for (int i = 0; i < 2; ++i) {
            int c = i*256 + tid;
            int row = c >> 2, c8 = c & 3;
            *(f16x8*)&a_lds[row][c8*8] =
                *(const f16x8*)(ao + (size_t)(m0+row)*DIM + k0 + c8*8);
        }
#pragma unroll
        for (int i = 0; i < 4; ++i) {
            int c = i*256 + tid;
            int row = c >> 3, c4 = c & 7;
            float4 v = *(const float4*)(Wf + (size_t)(n0+row)*DIM + k0 + c4*4);
            f16x4 hh = { (f16)v.x, (f16)v.y, (f16)v.z, (f16)v.w };
            *(f16x4*)&b_lds[row][c4*4] = hh;
        }
        __syncthreads();
        f16x8 af[4], bfr[4];
#pragma unroll
        for (int mt = 0; mt < 4; ++mt) af[mt]  = *(const f16x8*)&a_lds[wm*64 + mt*16 + mrow][qd*8];
#pragma unroll
        for (int nt = 0; nt < 4; ++nt) bfr[nt] = *(const f16x8*)&b_lds[wn*64 + nt*16 + mrow][qd*8];
#pragma unroll
        for (int mt = 0; mt < 4; ++mt)
#pragma unroll
            for (int nt = 0; nt < 4; ++nt)
                acc[mt][nt] = __builtin_amdgcn_mfma_f32_16x16x32_f16(af[mt], bfr[nt], acc[mt][nt], 0,0,0);
    }
#pragma unroll
    for (int mt = 0; mt < 4; ++mt)
#pragma unroll
        for (int r = 0; r < 4; ++r) {
            size_t grow = (size_t)(m0 + wm*64 + mt*16 + qd*4 + r) * DIM;
#pragma unroll
            for (int nt = 0; nt < 4; ++nt) {
                int col = n0 + wn*64 + nt*16 + mrow;
                out[grow + col] = acc[mt][nt][r] + bv[nt];
            }
        }
}

// ---------------------------------------------------------------------------
extern "C" void kernel_launch(void* const* d_in, const int* in_sizes, int n_in,
                              void* d_out, int out_size, void* d_ws, size_t ws_size,
                              hipStream_t stream)
{
    const float* x   = (const float*)d_in[0];
    const float* y   = (const float*)d_in[1];
    const float* Wq  = (const float*)d_in[2];
    const float* bq  = (const float*)d_in[3];
    const float* Wqv = (const float*)d_in[4];
    const float* bqv = (const float*)d_in[5];
    const float* Wk  = (const float*)d_in[6];
    const float* bk  = (const float*)d_in[7];
    const float* Wkv = (const float*)d_in[8];
    const float* bkv = (const float*)d_in[9];
    const float* Wf  = (const float*)d_in[10];
    const float* bf  = (const float*)d_in[11];
    float* out = (float*)d_out;

    f16* qh  = (f16*)d_ws;       // NEL f16 each; 80 MB total
    f16* qvh = qh  + NEL;
    f16* kP  = qvh + NEL;        // fragment-packed K
    f16* vP  = kP  + NEL;        // fragment-packed V
    f16* aob = vP  + NEL;

    proj_gemm<<<dim3(4, 128, 4), 256, 0, stream>>>(
        x, y, Wq, bq, Wqv, bqv, Wk, bk, Wkv, bkv, qh, qvh, kP, vP);
    attn_kernel<<<dim3(256), 512, 0, stream>>>(qh, kP, vP, qvh, aob);
    final_gemm<<<dim3(4, 128), 256, 0, stream>>>(aob, Wf, bf, out);
}

// Round 5
// 594.543 us; speedup vs baseline: 1.3077x; 1.3077x over previous
//
#include <hip/hip_runtime.h>

typedef _Float16 f16;
typedef _Float16 f16x8 __attribute__((ext_vector_type(8)));
typedef _Float16 f16x4 __attribute__((ext_vector_type(4)));
typedef float    f32x4 __attribute__((ext_vector_type(4)));
typedef float    f32x16 __attribute__((ext_vector_type(16)));

#define NB 4
#define SEQ 4096
#define DIM 512
#define MTOT (NB*SEQ)   // 16384
#define NEL ((size_t)MTOT*DIM)

// ---------------------------------------------------------------------------
// Projection GEMM: out[m,n] = f16( sum_k A[m,k] * W[n,k] + bias[n] )
// p: 0:q natural  1:qv natural  2:k fragment-packed  3:kv fragment-packed
// Packed layouts (unit = 16B = 8 f16, per 32-row KV tile gt = g>>5):
//  K: u = ((gt*2 + h)*16 + s)*64 + hi*32 + col   elem j
//     where col=g&31, d = h*256 + s*16 + hi*8 + j
//  V: u = ((gt*16 + c32)*2 + ks)*64 + hi*32 + cl  elem j
//     where kv=g&31 = ks*16+hi*8+j, d = c32*32 + cl
// Both give 1KB-contiguous wave fragments -> DMA linearly into LDS.
// ---------------------------------------------------------------------------
__global__ __launch_bounds__(256) void proj_gemm(
    const float* __restrict__ x, const float* __restrict__ y,
    const float* __restrict__ Wq, const float* __restrict__ bq,
    const float* __restrict__ Wqv, const float* __restrict__ bqv,
    const float* __restrict__ Wk, const float* __restrict__ bk,
    const float* __restrict__ Wkv, const float* __restrict__ bkv,
    f16* __restrict__ qh, f16* __restrict__ qvh,
    f16* __restrict__ kP, f16* __restrict__ vP)
{
    __shared__ __attribute__((aligned(16))) f16 a_lds[128][40];
    __shared__ __attribute__((aligned(16))) f16 b_lds[128][40];

    const int p = blockIdx.z;
    const float* A    = (p < 2) ? x : y;
    const float* W    = (p==0)?Wq:(p==1)?Wqv:(p==2)?Wk:Wkv;
    const float* bias = (p==0)?bq:(p==1)?bqv:(p==2)?bk:bkv;

    const int m0 = blockIdx.y * 128, n0 = blockIdx.x * 128;
    const int tid = threadIdx.x, lane = tid & 63, wv = tid >> 6;
    const int wm = wv >> 1, wn = wv & 1, mrow = lane & 15, qd = lane >> 4;

    f32x4 acc[4][4];
#pragma unroll
    for (int mt = 0; mt < 4; ++mt)
#pragma unroll
        for (int nt = 0; nt < 4; ++nt) acc[mt][nt] = (f32x4){0.f,0.f,0.f,0.f};

    float bv[4];
#pragma unroll
    for (int nt = 0; nt < 4; ++nt) bv[nt] = bias[n0 + wn*64 + nt*16 + mrow];

    for (int k0 = 0; k0 < DIM; k0 += 32) {
        __syncthreads();
#pragma unroll
        for (int i = 0; i < 4; ++i) {
            int c = i*256 + tid;
            int row = c >> 3, c4 = c & 7;
            float4 v = *(const float4*)(A + (size_t)(m0+row)*DIM + k0 + c4*4);
            f16x4 hh = { (f16)v.x, (f16)v.y, (f16)v.z, (f16)v.w };
            *(f16x4*)&a_lds[row][c4*4] = hh;
        }
#pragma unroll
        for (int i = 0; i < 4; ++i) {
            int c = i*256 + tid;
            int row = c >> 3, c4 = c & 7;
            float4 v = *(const float4*)(W + (size_t)(n0+row)*DIM + k0 + c4*4);
            f16x4 hh = { (f16)v.x, (f16)v.y, (f16)v.z, (f16)v.w };
            *(f16x4*)&b_lds[row][c4*4] = hh;
        }
        __syncthreads();
        f16x8 af[4], bfr[4];
#pragma unroll
        for (int mt = 0; mt < 4; ++mt) af[mt]  = *(const f16x8*)&a_lds[wm*64 + mt*16 + mrow][qd*8];
#pragma unroll
        for (int nt = 0; nt < 4; ++nt) bfr[nt] = *(const f16x8*)&b_lds[wn*64 + nt*16 + mrow][qd*8];
#pragma unroll
        for (int mt = 0; mt < 4; ++mt)
#pragma unroll
            for (int nt = 0; nt < 4; ++nt)
                acc[mt][nt] = __builtin_amdgcn_mfma_f32_16x16x32_f16(af[mt], bfr[nt], acc[mt][nt], 0,0,0);
    }

#pragma unroll
    for (int mt = 0; mt < 4; ++mt)
#pragma unroll
        for (int r = 0; r < 4; ++r) {
            int g = m0 + wm*64 + mt*16 + qd*4 + r;
#pragma unroll
            for (int nt = 0; nt < 4; ++nt) {
                int d = n0 + wn*64 + nt*16 + mrow;
                f16 val = (f16)(acc[mt][nt][r] + bv[nt]);
                if (p == 0) {
                    qh[(size_t)g*DIM + d] = val;
                } else if (p == 1) {
                    qvh[(size_t)g*DIM + d] = val;
                } else if (p == 2) {
                    int gt = g >> 5, col = g & 31;
                    int h2 = d >> 8, dl = d & 255;
                    int s = dl >> 4, hi = (dl >> 3) & 1, j = d & 7;
                    size_t u = ((size_t)(gt*2 + h2)*16 + s)*64 + hi*32 + col;
                    kP[u*8 + j] = val;
                } else {
                    int gt = g >> 5, kvr = g & 31;
                    int ks = kvr >> 4, hi = (kvr >> 3) & 1, jj = kvr & 7;
                    int c32 = d >> 5, cl2 = d & 31;
                    size_t u = ((size_t)(gt*16 + c32)*2 + ks)*64 + hi*32 + cl2;
                    vP[u*8 + jj] = val;
                }
            }
        }
}

// ---------------------------------------------------------------------------
// global -> LDS direct DMA, 16B per lane. LDS dest wave-uniform; HW adds
// lane*16. Global src per-lane.
// ---------------------------------------------------------------------------
__device__ __forceinline__ void gl_lds16(const f16* g, f16* l)
{
    __builtin_amdgcn_global_load_lds(
        (const __attribute__((address_space(1))) void*)g,
        (__attribute__((address_space(3))) void*)l, 16, 0, 0);
}

// max over each 32-lane group (all lanes receive result).
__device__ __forceinline__ float rowmax32(float v)
{
    int x;
    x = __builtin_amdgcn_update_dpp(__builtin_bit_cast(int, v), __builtin_bit_cast(int, v), 0x111, 0xF, 0xF, false);
    v = fmaxf(v, __builtin_bit_cast(float, x));
    x = __builtin_amdgcn_update_dpp(__builtin_bit_cast(int, v), __builtin_bit_cast(int, v), 0x112, 0xF, 0xF, false);
    v = fmaxf(v, __builtin_bit_cast(float, x));
    x = __builtin_amdgcn_update_dpp(__builtin_bit_cast(int, v), __builtin_bit_cast(int, v), 0x114, 0xF, 0xF, false);
    v = fmaxf(v, __builtin_bit_cast(float, x));
    x = __builtin_amdgcn_update_dpp(__builtin_bit_cast(int, v), __builtin_bit_cast(int, v), 0x118, 0xF, 0xF, false);
    v = fmaxf(v, __builtin_bit_cast(float, x));
    float a = __builtin_bit_cast(float, __builtin_amdgcn_ds_swizzle(__builtin_bit_cast(int, v), 0x01E0)); // lane 15
    float b = __builtin_bit_cast(float, __builtin_amdgcn_ds_swizzle(__builtin_bit_cast(int, v), 0x03E0)); // lane 31
    return fmaxf(a, b);
}

// ---------------------------------------------------------------------------
// Flash attention v6: 256 blocks (1/CU), 512 thr / 8 waves (2/SIMD),
// producer/consumer wave specialization. Per 32-row KV tile:
//  S-waves (w<4: qg x d-half h): QK^T partial (16 mfma 32x32x16, K from
//    LDS-staged packed frags) -> f32 exchange with partner half -> full S ->
//    rowmax(DPP) + defer-max(THR=8) -> P(f16)+alpha+flag to LDS.
//  O-waves (w>=4: qg x d-half dh): rescale-on-flag, PV (16 mfma) + l via
//    ones-MFMA, o = 32Q x 256d = 128 regs. One S + one O wave per SIMD:
//    softmax VALU overlaps PV MFMA.
// K/V DMA'd (global_load_lds) double-buffered: K by S-waves 2 tiles ahead,
// V by O-waves 1 ahead; issued a full phase before the barrier that drains.
// Split loops (wave-uniform branch) keep S/O register budgets separate;
// barrier counts identical (2/iter, 129 iters + 1 prologue).
// LDS: 64K kbuf + 64K vbuf + 16K xch + 5K plds + 10K alds = 159 KB.
// ---------------------------------------------------------------------------
__global__ __launch_bounds__(512, 2) void attn_kernel(
    const f16* __restrict__ qh, const f16* __restrict__ kP,
    const f16* __restrict__ vP, const f16* __restrict__ qvh,
    f16* __restrict__ ao)
{
    __shared__ __attribute__((aligned(16))) f16 kbuf[2][16384];   // 64 KB
    __shared__ __attribute__((aligned(16))) f16 vbuf[2][16384];   // 64 KB
    __shared__ __attribute__((aligned(16))) f32x4 xch[2][2][4][64]; // 16 KB
    __shared__ __attribute__((aligned(16))) f16 plds[2][32][40];  // 5 KB
    __shared__ float alds[2][64][20];                             // 10 KB
    __shared__ int flagLds[2];

    const int xcd = blockIdx.x & 7;
    const int b   = xcd >> 1;                          // batch -> XCD pair
    const int qt  = (blockIdx.x >> 3) * 2 + (xcd & 1); // 0..63
    const int tid = threadIdx.x, lane = tid & 63, w = tid >> 6;
    const int cl = lane & 31, lh = lane >> 5;

    const f16* kPb = kP + ((size_t)b << 21);
    const f16* vPb = vP + ((size_t)b << 21);

    if (w < 4) {
        // ================= S-waves: scores + softmax =================
        const int qg = w & 1, h = (w >> 1) & 1;

        // prologue: DMA K0 -> kbuf[0]
#pragma unroll
        for (int c = 0; c < 8; ++c) {
            const int ub = (c*4 + w) * 64;
            gl_lds16(kPb + (size_t)(ub + lane)*8, (f16*)&kbuf[0][0] + ub*8);
        }
        __syncthreads();

        // Q A-frags for this d-half (row = cl, k = s*16 + lh*8 + j)
        const size_t qoff = ((size_t)b*SEQ + qt*64 + qg*32 + cl)*DIM + h*256 + lh*8;
        f16x8 qf[16];
#pragma unroll
        for (int s = 0; s < 16; ++s) qf[s] = *(const f16x8*)(qh + qoff + s*16);

        float m_[16];
#pragma unroll
        for (int i = 0; i < 16; ++i) m_[i] = -INFINITY;

        for (int j = -1; j < 128; ++j) {
            // phase 1: DMA K[j+2] -> kbuf[j&1]
            if (j <= 125) {
                const f16* src = kPb + (size_t)(j + 2) * 16384;
                f16* dst = (f16*)&kbuf[j & 1][0];
#pragma unroll
                for (int c = 0; c < 8; ++c) {
                    const int ub = (c*4 + w) * 64;
                    gl_lds16(src + (size_t)(ub + lane)*8, dst + ub*8);
                }
            }
            // phase 2: partial S(j+1), two MFMA chains
            f32x16 sacc;
            if (j <= 126) {
                const f16* kb = &kbuf[(j + 1) & 1][h*8192];
                f32x16 sa, sb;
#pragma unroll
                for (int i = 0; i < 16; ++i) { sa[i] = 0.f; sb[i] = 0.f; }
#pragma unroll
                for (int s = 0; s < 8; ++s) {
                    f16x8 k0 = *(const f16x8*)&kb[(2*s)*512 + lane*8];
                    f16x8 k1 = *(const f16x8*)&kb[(2*s + 1)*512 + lane*8];
                    sa = __builtin_amdgcn_mfma_f32_32x32x16_f16(qf[2*s],     k0, sa, 0,0,0);
                    sb = __builtin_amdgcn_mfma_f32_32x32x16_f16(qf[2*s + 1], k1, sb, 0,0,0);
                }
#pragma unroll
                for (int i = 0; i < 16; ++i) sacc[i] = sa[i] + sb[i];
#pragma unroll
                for (int ch = 0; ch < 4; ++ch)
                    xch[qg][h][ch][lane] =
                        (f32x4){ sacc[ch*4], sacc[ch*4+1], sacc[ch*4+2], sacc[ch*4+3] };
            }
            __syncthreads();                                   // bar1
            // phase 4: full S, softmax, P/alpha/flag
            if (j <= 126) {
                f32x16 Sf;
#pragma unroll
                for (int ch = 0; ch < 4; ++ch) {
                    f32x4 pr = xch[qg][h ^ 1][ch][lane];
#pragma unroll
                    for (int r = 0; r < 4; ++r) Sf[ch*4+r] = sacc[ch*4+r] + pr[r];
                }
                float pm[16];
#pragma unroll
                for (int i = 0; i < 16; ++i) pm[i] = rowmax32(Sf[i]);
                bool need = false;
#pragma unroll
                for (int i = 0; i < 16; ++i) need = need || (pm[i] > m_[i] + 8.f);
                if (__any((int)need)) {
                    float al[16];
#pragma unroll
                    for (int i = 0; i < 16; ++i) {
                        float mn = fmaxf(m_[i], pm[i]);
                        al[i] = __expf(m_[i] - mn);
                        m_[i] = mn;
                    }
                    if (h == 0) {
#pragma unroll
                        for (int i = 0; i < 16; ++i) alds[qg][lane][i] = al[i];
                        if (lane == 0) flagLds[qg] = 1;
                    }
                } else {
                    if (h == 0 && lane == 0) flagLds[qg] = 0;
                }
                if (h == 0) {
#pragma unroll
                    for (int i = 0; i < 8; ++i) {
                        int row = (i & 3) + 8*(i >> 2) + 4*lh;         // rows 0..15
                        plds[qg][row][cl] = (f16)__expf(Sf[i] - m_[i]);
                    }
                } else {
#pragma unroll
                    for (int i = 8; i < 16; ++i) {
                        int row = (i & 3) + 8*(i >> 2) + 4*lh;         // rows 16..31
                        plds[qg][row][cl] = (f16)__expf(Sf[i] - m_[i]);
                    }
                }
            }
            __syncthreads();                                   // bar2
        }
    } else {
        // ================= O-waves: PV accumulation =================
        const int qg = w & 1, dh = (w >> 1) & 1;
        __syncthreads();   // match S prologue barrier

        f32x16 o_[8];
        f32x16 l16;
#pragma unroll
        for (int i = 0; i < 16; ++i) {
            o_[0][i]=0.f; o_[1][i]=0.f; o_[2][i]=0.f; o_[3][i]=0.f;
            o_[4][i]=0.f; o_[5][i]=0.f; o_[6][i]=0.f; o_[7][i]=0.f;
            l16[i]=0.f;
        }
        const f16x8 onesv = {(f16)1.f,(f16)1.f,(f16)1.f,(f16)1.f,
                             (f16)1.f,(f16)1.f,(f16)1.f,(f16)1.f};

        for (int j = -1; j < 128; ++j) {
            // phase 1: DMA V[j+1] -> vbuf[(j+1)&1]
            if (j <= 126) {
                const f16* src = vPb + (size_t)(j + 1) * 16384;
                f16* dst = (f16*)&vbuf[(j + 1) & 1][0];
#pragma unroll
                for (int c = 0; c < 8; ++c) {
                    const int ub = (c*4 + (w - 4)) * 64;
                    gl_lds16(src + (size_t)(ub + lane)*8, dst + ub*8);
                }
            }
            // phase 2: PV(j)
            if (j >= 0) {
                if (flagLds[qg]) {
#pragma unroll
                    for (int i = 0; i < 16; ++i) {
                        float a = alds[qg][lane][i];
                        o_[0][i]*=a; o_[1][i]*=a; o_[2][i]*=a; o_[3][i]*=a;
                        o_[4][i]*=a; o_[5][i]*=a; o_[6][i]*=a; o_[7][i]*=a;
                        l16[i]*=a;
                    }
                }
                f16x8 pa0 = *(const f16x8*)&plds[qg][cl][lh*8];
                f16x8 pa1 = *(const f16x8*)&plds[qg][cl][16 + lh*8];
                l16 = __builtin_amdgcn_mfma_f32_32x32x16_f16(pa0, onesv, l16, 0,0,0);
                l16 = __builtin_amdgcn_mfma_f32_32x32x16_f16(pa1, onesv, l16, 0,0,0);
                const f16* vb = &vbuf[j & 1][0];
#pragma unroll
                for (int c = 0; c < 8; ++c) {
                    f16x8 v0 = *(const f16x8*)&vb[((dh*8 + c)*2 + 0)*512 + lane*8];
                    f16x8 v1 = *(const f16x8*)&vb[((dh*8 + c)*2 + 1)*512 + lane*8];
                    o_[c] = __builtin_amdgcn_mfma_f32_32x32x16_f16(pa0, v0, o_[c], 0,0,0);
                    o_[c] = __builtin_amdgcn_mfma_f32_32x32x16_f16(pa1, v1, o_[c], 0,0,0);
                }
            }
            __syncthreads();                                   // bar1
            __syncthreads();                                   // bar2
        }

        // epilogue: rows qt*64+qg*32+row, cols dh*256 + c*32 + cl
#pragma unroll
        for (int i = 0; i < 16; ++i) {
            float inv = 1.f / l16[i];
            int row = (i & 3) + 8*(i >> 2) + 4*lh;
            size_t grow = ((size_t)b*SEQ + qt*64 + qg*32 + row)*DIM + dh*256;
#pragma unroll
            for (int c = 0; c < 8; ++c) {
                int col = c*32 + cl;
                float val = o_[c][i]*inv + (float)qvh[grow + col];
                ao[grow + col] = (f16)val;
            }
        }
    }
}

// ---------------------------------------------------------------------------
// Final linear: out[m,n] = sum_k ao[m,k]*Wf[n,k] + bf[n]  (f32 out)
// ---------------------------------------------------------------------------
__global__ __launch_bounds__(256) void final_gemm(
    const f16* __restrict__ ao, const float* __restrict__ Wf,
    const float* __restrict__ bf, float* __restrict__ out)
{
    __shared__ __attribute__((aligned(16))) f16 a_lds[128][40];
    __shared__ __attribute__((aligned(16))) f16 b_lds[128][40];

    const int m0 = blockIdx.y * 128, n0 = blockIdx.x * 128;
    const int tid = threadIdx.x, lane = tid & 63, wv = tid >> 6;
    const int wm = wv >> 1, wn = wv & 1, mrow = lane & 15, qd = lane >> 4;

    f32x4 acc[4][4];
#pragma unroll
    for (int mt = 0; mt < 4; ++mt)
#pragma unroll
        for (int nt = 0; nt < 4; ++nt) acc[mt][nt] = (f32x4){0.f,0.f,0.f,0.f};

    float bv[4];
#pragma unroll
    for (int nt = 0; nt < 4; ++nt) bv[nt] = bf[n0 + wn*64 + nt*16 + mrow];

    for (int k0 = 0; k0 < DIM; k0 += 32) {
        __syncthreads();
#pragma unroll
        for (int i = 0; i < 2; ++i) {
            int c = i*256 + tid;
            int row = c >> 2, c8 = c & 3;
            *(f16x8*)&a_lds[row][c8*8] =
                *(const f16x8*)(ao + (size_t)(m0+row)*DIM + k0 + c8*8);
        }
#pragma unroll
        for (int i = 0; i < 4; ++i) {
            int c = i*256 + tid;
            int row = c >> 3, c4 = c & 7;
            float4 v = *(const float4*)(Wf + (size_t)(n0+row)*DIM + k0 + c4*4);
            f16x4 hh = { (f16)v.x, (f16)v.y, (f16)v.z, (f16)v.w };
            *(f16x4*)&b_lds[row][c4*4] = hh;
        }
        __syncthreads();
        f16x8 af[4], bfr[4];
#pragma unroll
        for (int mt = 0; mt < 4; ++mt) af[mt]  = *(const f16x8*)&a_lds[wm*64 + mt*16 + mrow][qd*8];
#pragma unroll
        for (int nt = 0; nt < 4; ++nt) bfr[nt] = *(const f16x8*)&b_lds[wn*64 + nt*16 + mrow][qd*8];
#pragma unroll
        for (int mt = 0; mt < 4; ++mt)
#pragma unroll
            for (int nt = 0; nt < 4; ++nt)
                acc[mt][nt] = __builtin_amdgcn_mfma_f32_16x16x32_f16(af[mt], bfr[nt], acc[mt][nt], 0,0,0);
    }
#pragma unroll
    for (int mt = 0; mt < 4; ++mt)
#pragma unroll
        for (int r = 0; r < 4; ++r) {
            size_t grow = (size_t)(m0 + wm*64 + mt*16 + qd*4 + r) * DIM;
#pragma unroll
            for (int nt = 0; nt < 4; ++nt) {
                int col = n0 + wn*64 + nt*16 + mrow;
                out[grow + col] = acc[mt][nt][r] + bv[nt];
            }
        }
}

// ---------------------------------------------------------------------------
extern "C" void kernel_launch(void* const* d_in, const int* in_sizes, int n_in,
                              void* d_out, int out_size, void* d_ws, size_t ws_size,
                              hipStream_t stream)
{
    const float* x   = (const float*)d_in[0];
    const float* y   = (const float*)d_in[1];
    const float* Wq  = (const float*)d_in[2];
    const float* bq  = (const float*)d_in[3];
    const float* Wqv = (const float*)d_in[4];
    const float* bqv = (const float*)d_in[5];
    const float* Wk  = (const float*)d_in[6];
    const float* bk  = (const float*)d_in[7];
    const float* Wkv = (const float*)d_in[8];
    const float* bkv = (const float*)d_in[9];
    const float* Wf  = (const float*)d_in[10];
    const float* bf  = (const float*)d_in[11];
    float* out = (float*)d_out;

    f16* qh  = (f16*)d_ws;       // NEL f16 each; 80 MB total
    f16* qvh = qh  + NEL;
    f16* kP  = qvh + NEL;        // fragment-packed K
    f16* vP  = kP  + NEL;        // fragment-packed V
    f16* aob = vP  + NEL;

    proj_gemm<<<dim3(4, 128, 4), 256, 0, stream>>>(
        x, y, Wq, bq, Wqv, bqv, Wk, bk, Wkv, bkv, qh, qvh, kP, vP);
    attn_kernel<<<dim3(256), 512, 0, stream>>>(qh, kP, vP, qvh, aob);
    final_gemm<<<dim3(4, 128), 256, 0, stream>>>(aob, Wf, bf, out);
}